// Round 1
// baseline (468.449 us; speedup 1.0000x reference)
//
#include <hip/hip_runtime.h>
#include <stdint.h>

#define NCLUST 8192
#define BATCH 256
#define DIM 1024
#define NFEAT 65536
#define TEMP_INV 20.0f
#define TOPP 0.1f
#define EPSC 1e-6f

typedef __attribute__((ext_vector_type(8))) short short8;
typedef __attribute__((ext_vector_type(4))) float floatx4;

__device__ __forceinline__ unsigned short f2bf(float f) {
    uint32_t u = __float_as_uint(f);
    uint32_t r = u + 0x7FFFu + ((u >> 16) & 1u);
    return (unsigned short)(r >> 16);
}

__device__ __forceinline__ float block_sum(float v, float* lds4) {
    for (int o = 32; o > 0; o >>= 1) v += __shfl_down(v, o, 64);
    __syncthreads();                       // protect lds4 from previous use
    if ((threadIdx.x & 63) == 0) lds4[threadIdx.x >> 6] = v;
    __syncthreads();
    return lds4[0] + lds4[1] + lds4[2] + lds4[3];
}

// ---------------- K0: zero counts + output ----------------
__global__ void k_init(int* counts, float* out) {
    int i = blockIdx.x * 256 + threadIdx.x;
    if (i < NCLUST) counts[i] = 0;
    if (i == 0) out[0] = 0.0f;
}

// ---------------- K1: L2-normalize rows of results, cast bf16 ----------------
__global__ void k_norm(const float* __restrict__ results, unsigned short* __restrict__ inputsB) {
    __shared__ float lds4[4];
    int b = blockIdx.x, t = threadIdx.x;
    const float4* rp = (const float4*)(results + (size_t)b * DIM);
    float4 v = rp[t];
    float ss = v.x * v.x + v.y * v.y + v.z * v.z + v.w * v.w;
    float S = block_sum(ss, lds4);
    float rn = rsqrtf(S);
    ushort4 o;
    o.x = f2bf(v.x * rn); o.y = f2bf(v.y * rn); o.z = f2bf(v.z * rn); o.w = f2bf(v.w * rn);
    *(ushort4*)(inputsB + (size_t)b * DIM + t * 4) = o;
}

// ---------------- K2: label histogram ----------------
__global__ void k_hist(const int* __restrict__ labels, int* __restrict__ counts) {
    int n = blockIdx.x * 256 + threadIdx.x;
    if (n < NFEAT) atomicAdd(&counts[labels[n]], 1);
}

// ---------------- K3: exclusive scan of counts -> offsets, cursor ----------------
__global__ void k_scan(const int* __restrict__ counts, int* __restrict__ offsets, int* __restrict__ cursor) {
    __shared__ int ch[256];
    int t = threadIdx.x;
    int base = t * 32;
    int s = 0;
    for (int i = 0; i < 32; i++) s += counts[base + i];
    ch[t] = s;
    __syncthreads();
    for (int off = 1; off < 256; off <<= 1) {
        int v = ch[t];
        int a = (t >= off) ? ch[t - off] : 0;
        __syncthreads();
        ch[t] = v + a;
        __syncthreads();
    }
    int excl = (t > 0) ? ch[t - 1] : 0;
    for (int i = 0; i < 32; i++) {
        offsets[base + i] = excl;
        cursor[base + i] = excl;
        excl += counts[base + i];
    }
}

// ---------------- K4: scatter row indices into per-cluster lists ----------------
__global__ void k_scatter(const int* __restrict__ labels, int* __restrict__ cursor, int* __restrict__ idxlist) {
    int n = blockIdx.x * 256 + threadIdx.x;
    if (n < NFEAT) {
        int l = labels[n];
        int pos = atomicAdd(&cursor[l], 1);
        idxlist[pos] = n;
    }
}

// ---------------- K5: per-cluster feature sum, scale by 1/(TEMP*n), cast bf16 ----------------
__global__ void k_csum(const float* __restrict__ features, const int* __restrict__ counts,
                       const int* __restrict__ offsets, const int* __restrict__ idxlist,
                       unsigned short* __restrict__ FsumB) {
    int c = blockIdx.x, t = threadIdx.x;
    int cnt = counts[c], off = offsets[c];
    float ax = 0.f, ay = 0.f, az = 0.f, aw = 0.f;
    for (int j = 0; j < cnt; j++) {
        int r = idxlist[off + j];
        const float4* fp = (const float4*)(features + (size_t)r * DIM);
        float4 v = fp[t];
        ax += v.x; ay += v.y; az += v.z; aw += v.w;
    }
    int d = (cnt > 0) ? cnt : 1;
    float sc = TEMP_INV / (float)d;
    ushort4 o;
    o.x = f2bf(ax * sc); o.y = f2bf(ay * sc); o.z = f2bf(az * sc); o.w = f2bf(aw * sc);
    *(ushort4*)(FsumB + (size_t)c * DIM + t * 4) = o;
}

// ---------------- K6: MFMA bf16 GEMM: sims[b][c] = inputs[b] . FsumB[c] ----------------
// A = inputsB [256][1024], B^T = FsumB [8192][1024], C = sims [256][8192]
#define BM 128
#define BN 64
#define BK 64
#define LDT 72  // 64 + 8 pad (ushorts) -> 144B row stride, kills b128 bank conflicts

__global__ __launch_bounds__(256) void k_gemm(const unsigned short* __restrict__ A,
                                              const unsigned short* __restrict__ B,
                                              float* __restrict__ C) {
    __shared__ unsigned short As[BM * LDT];
    __shared__ unsigned short Bs[BN * LDT];
    int tid = threadIdx.x;
    int bn0 = blockIdx.x * BN;
    int bm0 = blockIdx.y * BM;
    int w = tid >> 6, lane = tid & 63;
    int quad = lane >> 4, l16 = lane & 15;
    int wm = (w >> 1) * 64;  // wave m-origin within block tile
    int wn = (w & 1) * 32;   // wave n-origin
    floatx4 acc[4][2];
    for (int im = 0; im < 4; im++)
        for (int in = 0; in < 2; in++)
            acc[im][in] = (floatx4){0.f, 0.f, 0.f, 0.f};

    int kg = tid & 7;   // k-group of 8 elements
    int rr = tid >> 3;  // 0..31

    for (int k0 = 0; k0 < DIM; k0 += BK) {
        // stage A tile: 128 x 64
        for (int r = 0; r < 4; r++) {
            int m = rr + r * 32;
            uint4 v = *(const uint4*)(A + (size_t)(bm0 + m) * DIM + k0 + kg * 8);
            *(uint4*)&As[m * LDT + kg * 8] = v;
        }
        // stage B tile: 64 x 64
        for (int r = 0; r < 2; r++) {
            int n = rr + r * 32;
            uint4 v = *(const uint4*)(B + (size_t)(bn0 + n) * DIM + k0 + kg * 8);
            *(uint4*)&Bs[n * LDT + kg * 8] = v;
        }
        __syncthreads();
        for (int ks = 0; ks < BK; ks += 32) {
            short8 af[4], bf[2];
            for (int im = 0; im < 4; im++)
                af[im] = *(const short8*)&As[(wm + im * 16 + l16) * LDT + ks + quad * 8];
            for (int in = 0; in < 2; in++)
                bf[in] = *(const short8*)&Bs[(wn + in * 16 + l16) * LDT + ks + quad * 8];
            for (int im = 0; im < 4; im++)
                for (int in = 0; in < 2; in++)
                    acc[im][in] = __builtin_amdgcn_mfma_f32_16x16x32_bf16(af[im], bf[in], acc[im][in], 0, 0, 0);
        }
        __syncthreads();
    }
    // epilogue: D row = quad*4 + r (m), col = l16 (n)
    for (int im = 0; im < 4; im++)
        for (int in = 0; in < 2; in++) {
            int row = bm0 + wm + im * 16 + quad * 4;
            int col = bn0 + wn + in * 16 + l16;
            for (int r = 0; r < 4; r++)
                C[(size_t)(row + r) * NCLUST + col] = acc[im][in][r];
        }
}

// ---------------- K7: truncated-softmax focal loss per row (bisection select) ----------------
__global__ __launch_bounds__(256) void k_focal(const float* __restrict__ sims, const int* __restrict__ counts,
                                               const int* __restrict__ indexes, const int* __restrict__ labels,
                                               float* __restrict__ out) {
    __shared__ float lds4[4];
    __shared__ float s_et;
    int b = blockIdx.x, tid = threadIdx.x;
    int t = labels[indexes[b]];
    const float* srow = sims + (size_t)b * NCLUST;

    float X[32];
    float local = 0.f;
    for (int r = 0; r < 32; r++) {
        int i = r * 256 + tid;
        float v = srow[i];
        bool m = counts[i] > 0;
        float x = (i == t || !m) ? 0.0f : expf(v);
        if (i == t) s_et = expf(v);  // target cluster always non-empty
        X[r] = x;
        local += x;
    }
    float S = block_sum(local, lds4);  // barriers inside also publish s_et
    float T = TOPP * S;

    // bisection on float bit space: find boundary value x* where desc-cumsum crosses T
    unsigned lo = 0u, hi = 0x7F800000u;  // invariant: G(lo) >= T, G(hi) < T
    for (int it = 0; it < 31; it++) {
        unsigned mid = lo + ((hi - lo) >> 1);
        float v = __uint_as_float(mid);
        float g = 0.f;
        for (int r = 0; r < 32; r++) g += (X[r] >= v) ? X[r] : 0.f;
        g = block_sum(g, lds4);
        if (g >= T) lo = mid; else hi = mid;
    }
    float xs = __uint_as_float(lo);  // actual data value, > 0

    float sgt = 0.f, sge = 0.f, cgt = 0.f;
    for (int r = 0; r < 32; r++) {
        if (X[r] > xs) { sgt += X[r]; cgt += 1.f; }
        if (X[r] >= xs) sge += X[r];
    }
    sgt = block_sum(sgt, lds4);
    sge = block_sum(sge, lds4);
    cgt = block_sum(cgt, lds4);

    // crossing happens inside the run of values == xs:
    // csum candidates: sgt + j*xs, j = j0-1 and j0 (smallest j with sgt + j*xs >= T)
    float jf = (T - sgt) / xs;
    int j0 = (int)ceilf(jf);
    int mult = (int)rintf((sge - sgt) / xs);
    if (mult < 1) mult = 1;
    if (j0 < 1) j0 = 1;
    if (j0 > mult) j0 = mult;
    while (j0 > 1 && sgt + (float)(j0 - 1) * xs >= T) j0--;
    while (j0 < mult && sgt + (float)j0 * xs < T) j0++;
    float c_lo = sgt + (float)(j0 - 1) * xs;
    float c_hi = sgt + (float)j0 * xs;
    bool left_exists = ((int)cgt + j0) >= 2;                 // index i*-1 >= 0
    bool choose_left = left_exists && ((T - c_lo) <= (c_hi - T));  // argmin picks first on tie
    // if left candidate sits on the last element > x*, threshold = that element -> kept = sgt;
    // otherwise threshold = x* -> kept includes all ties -> sge
    float kept = (choose_left && j0 == 1) ? sgt : sge;

    if (tid == 0) {
        float et = s_et;
        float p = et / (et + kept + EPSC);
        float loss = -logf(p + EPSC);
        atomicAdd(out, loss * (1.0f / 256.0f));
    }
}

extern "C" void kernel_launch(void* const* d_in, const int* in_sizes, int n_in,
                              void* d_out, int out_size, void* d_ws, size_t ws_size,
                              hipStream_t stream) {
    const float* results = (const float*)d_in[0];
    const float* features = (const float*)d_in[1];
    const int* indexes = (const int*)d_in[2];
    const int* labels = (const int*)d_in[3];
    float* out = (float*)d_out;

    char* ws = (char*)d_ws;
    size_t off = 0;
    auto alloc = [&](size_t bytes) -> void* {
        void* p = ws + off;
        off += (bytes + 255) & ~(size_t)255;
        return p;
    };
    unsigned short* inputsB = (unsigned short*)alloc((size_t)BATCH * DIM * 2);
    unsigned short* FsumB = (unsigned short*)alloc((size_t)NCLUST * DIM * 2);
    float* sims = (float*)alloc((size_t)BATCH * NCLUST * 4);
    int* counts = (int*)alloc((size_t)NCLUST * 4);
    int* offsets = (int*)alloc((size_t)NCLUST * 4);
    int* cursor = (int*)alloc((size_t)NCLUST * 4);
    int* idxlist = (int*)alloc((size_t)NFEAT * 4);

    k_init<<<dim3(NCLUST / 256), dim3(256), 0, stream>>>(counts, out);
    k_norm<<<dim3(BATCH), dim3(256), 0, stream>>>(results, inputsB);
    k_hist<<<dim3(NFEAT / 256), dim3(256), 0, stream>>>(labels, counts);
    k_scan<<<dim3(1), dim3(256), 0, stream>>>(counts, offsets, cursor);
    k_scatter<<<dim3(NFEAT / 256), dim3(256), 0, stream>>>(labels, cursor, idxlist);
    k_csum<<<dim3(NCLUST), dim3(256), 0, stream>>>(features, counts, offsets, idxlist, FsumB);
    k_gemm<<<dim3(NCLUST / BN, BATCH / BM), dim3(256), 0, stream>>>(inputsB, FsumB, sims);
    k_focal<<<dim3(BATCH), dim3(256), 0, stream>>>(sims, counts, indexes, labels, out);
}

// Round 2
// 449.705 us; speedup vs baseline: 1.0417x; 1.0417x over previous
//
#include <hip/hip_runtime.h>
#include <stdint.h>

#define NCLUST 8192
#define BATCH 256
#define DIM 1024
#define NFEAT 65536
#define TEMP_INV 20.0f
#define TOPP 0.1f
#define EPSC 1e-6f

typedef __attribute__((ext_vector_type(8))) short short8;
typedef __attribute__((ext_vector_type(4))) float floatx4;

__device__ __forceinline__ unsigned short f2bf(float f) {
    uint32_t u = __float_as_uint(f);
    uint32_t r = u + 0x7FFFu + ((u >> 16) & 1u);
    return (unsigned short)(r >> 16);
}

__device__ __forceinline__ float block_sum(float v, float* lds4) {
    for (int o = 32; o > 0; o >>= 1) v += __shfl_down(v, o, 64);
    __syncthreads();                       // protect lds4 from previous use
    if ((threadIdx.x & 63) == 0) lds4[threadIdx.x >> 6] = v;
    __syncthreads();
    return lds4[0] + lds4[1] + lds4[2] + lds4[3];
}

// ---------------- K0: zero counts + output ----------------
__global__ void k_init(int* counts, float* out) {
    int i = blockIdx.x * 256 + threadIdx.x;
    if (i < NCLUST) counts[i] = 0;
    if (i == 0) out[0] = 0.0f;
}

// ---------------- K1: L2-normalize rows of results + label histogram (fused) ----------------
__global__ void k_normhist(const float* __restrict__ results, unsigned short* __restrict__ inputsB,
                           const int* __restrict__ labels, int* __restrict__ counts) {
    __shared__ float lds4[4];
    int b = blockIdx.x, t = threadIdx.x;
    // histogram part: this block covers labels[b*256 .. b*256+255]
    atomicAdd(&counts[labels[b * 256 + t]], 1);
    // norm part
    const float4* rp = (const float4*)(results + (size_t)b * DIM);
    float4 v = rp[t];
    float ss = v.x * v.x + v.y * v.y + v.z * v.z + v.w * v.w;
    float S = block_sum(ss, lds4);
    float rn = rsqrtf(S);
    ushort4 o;
    o.x = f2bf(v.x * rn); o.y = f2bf(v.y * rn); o.z = f2bf(v.z * rn); o.w = f2bf(v.w * rn);
    *(ushort4*)(inputsB + (size_t)b * DIM + t * 4) = o;
}

// ---------------- K2: exclusive scan of counts -> offsets, cursor ----------------
__global__ void k_scan(const int* __restrict__ counts, int* __restrict__ offsets, int* __restrict__ cursor) {
    __shared__ int ch[256];
    int t = threadIdx.x;
    int base = t * 32;
    int c32[32];
    const int4* cp = (const int4*)(counts + base);
    #pragma unroll
    for (int i = 0; i < 8; i++) {
        int4 q = cp[i];
        c32[i * 4 + 0] = q.x; c32[i * 4 + 1] = q.y; c32[i * 4 + 2] = q.z; c32[i * 4 + 3] = q.w;
    }
    int s = 0;
    #pragma unroll
    for (int i = 0; i < 32; i++) s += c32[i];
    ch[t] = s;
    __syncthreads();
    for (int off = 1; off < 256; off <<= 1) {
        int v = ch[t];
        int a = (t >= off) ? ch[t - off] : 0;
        __syncthreads();
        ch[t] = v + a;
        __syncthreads();
    }
    int excl = (t > 0) ? ch[t - 1] : 0;
    #pragma unroll
    for (int i = 0; i < 32; i++) {
        offsets[base + i] = excl;
        cursor[base + i] = excl;
        excl += c32[i];
    }
}

// ---------------- K3: scatter row indices into per-cluster lists ----------------
__global__ void k_scatter(const int* __restrict__ labels, int* __restrict__ cursor, int* __restrict__ idxlist) {
    int n = blockIdx.x * 256 + threadIdx.x;
    if (n < NFEAT) {
        int l = labels[n];
        int pos = atomicAdd(&cursor[l], 1);
        idxlist[pos] = n;
    }
}

// ---------------- K4: per-cluster feature sum, scale by 1/(TEMP*n), cast bf16 ----------------
#define CCHUNK 256
__global__ __launch_bounds__(256) void k_csum(const float* __restrict__ features, const int* __restrict__ counts,
                       const int* __restrict__ offsets, const int* __restrict__ idxlist,
                       unsigned short* __restrict__ FsumB) {
    __shared__ int sidx[CCHUNK];
    int c = blockIdx.x, t = threadIdx.x;
    int cnt = counts[c], off = offsets[c];
    float a0x = 0.f, a0y = 0.f, a0z = 0.f, a0w = 0.f;
    float a1x = 0.f, a1y = 0.f, a1z = 0.f, a1w = 0.f;
    float a2x = 0.f, a2y = 0.f, a2z = 0.f, a2w = 0.f;
    float a3x = 0.f, a3y = 0.f, a3z = 0.f, a3w = 0.f;
    for (int base = 0; base < cnt; base += CCHUNK) {
        int m = min(CCHUNK, cnt - base);
        __syncthreads();
        if (t < m) sidx[t] = idxlist[off + base + t];
        __syncthreads();
        int j = 0;
        for (; j + 4 <= m; j += 4) {
            int r0 = sidx[j], r1 = sidx[j + 1], r2 = sidx[j + 2], r3 = sidx[j + 3];
            float4 v0 = ((const float4*)(features + (size_t)r0 * DIM))[t];
            float4 v1 = ((const float4*)(features + (size_t)r1 * DIM))[t];
            float4 v2 = ((const float4*)(features + (size_t)r2 * DIM))[t];
            float4 v3 = ((const float4*)(features + (size_t)r3 * DIM))[t];
            a0x += v0.x; a0y += v0.y; a0z += v0.z; a0w += v0.w;
            a1x += v1.x; a1y += v1.y; a1z += v1.z; a1w += v1.w;
            a2x += v2.x; a2y += v2.y; a2z += v2.z; a2w += v2.w;
            a3x += v3.x; a3y += v3.y; a3z += v3.z; a3w += v3.w;
        }
        for (; j < m; j++) {
            int r0 = sidx[j];
            float4 v0 = ((const float4*)(features + (size_t)r0 * DIM))[t];
            a0x += v0.x; a0y += v0.y; a0z += v0.z; a0w += v0.w;
        }
    }
    float ax = a0x + a1x + a2x + a3x;
    float ay = a0y + a1y + a2y + a3y;
    float az = a0z + a1z + a2z + a3z;
    float aw = a0w + a1w + a2w + a3w;
    int d = (cnt > 0) ? cnt : 1;
    float sc = TEMP_INV / (float)d;
    ushort4 o;
    o.x = f2bf(ax * sc); o.y = f2bf(ay * sc); o.z = f2bf(az * sc); o.w = f2bf(aw * sc);
    *(ushort4*)(FsumB + (size_t)c * DIM + t * 4) = o;
}

// ---------------- K5: MFMA bf16 GEMM: sims[b][c] = inputs[b] . FsumB[c] ----------------
// A = inputsB [256][1024], B^T = FsumB [8192][1024], C = sims [256][8192]
#define BM 64
#define BN 64
#define BK 64
#define LDT 72  // 64 + 8 pad (ushorts) -> 144B row stride, kills b128 bank conflicts

__global__ __launch_bounds__(256) void k_gemm(const unsigned short* __restrict__ A,
                                              const unsigned short* __restrict__ B,
                                              float* __restrict__ C) {
    __shared__ unsigned short As[BM * LDT];
    __shared__ unsigned short Bs[BN * LDT];
    int tid = threadIdx.x;
    int bn0 = blockIdx.x * BN;
    int bm0 = blockIdx.y * BM;
    int w = tid >> 6, lane = tid & 63;
    int quad = lane >> 4, l16 = lane & 15;
    int wm = (w >> 1) * 32;  // wave m-origin within block tile
    int wn = (w & 1) * 32;   // wave n-origin
    floatx4 acc[2][2];
    for (int im = 0; im < 2; im++)
        for (int in = 0; in < 2; in++)
            acc[im][in] = (floatx4){0.f, 0.f, 0.f, 0.f};

    int kg = tid & 7;   // k-group of 8 elements
    int rr = tid >> 3;  // 0..31

    for (int k0 = 0; k0 < DIM; k0 += BK) {
        // stage A tile: 64 x 64
        for (int r = 0; r < 2; r++) {
            int m = rr + r * 32;
            uint4 v = *(const uint4*)(A + (size_t)(bm0 + m) * DIM + k0 + kg * 8);
            *(uint4*)&As[m * LDT + kg * 8] = v;
        }
        // stage B tile: 64 x 64
        for (int r = 0; r < 2; r++) {
            int n = rr + r * 32;
            uint4 v = *(const uint4*)(B + (size_t)(bn0 + n) * DIM + k0 + kg * 8);
            *(uint4*)&Bs[n * LDT + kg * 8] = v;
        }
        __syncthreads();
        for (int ks = 0; ks < BK; ks += 32) {
            short8 af[2], bf[2];
            for (int im = 0; im < 2; im++)
                af[im] = *(const short8*)&As[(wm + im * 16 + l16) * LDT + ks + quad * 8];
            for (int in = 0; in < 2; in++)
                bf[in] = *(const short8*)&Bs[(wn + in * 16 + l16) * LDT + ks + quad * 8];
            for (int im = 0; im < 2; im++)
                for (int in = 0; in < 2; in++)
                    acc[im][in] = __builtin_amdgcn_mfma_f32_16x16x32_bf16(af[im], bf[in], acc[im][in], 0, 0, 0);
        }
        __syncthreads();
    }
    // epilogue: D row = quad*4 + r (m), col = l16 (n)
    for (int im = 0; im < 2; im++)
        for (int in = 0; in < 2; in++) {
            int row = bm0 + wm + im * 16 + quad * 4;
            int col = bn0 + wn + in * 16 + l16;
            for (int r = 0; r < 4; r++)
                C[(size_t)(row + r) * NCLUST + col] = acc[im][in][r];
        }
}

// ---------------- K6: truncated-softmax focal loss per row (bisection select) ----------------
__global__ __launch_bounds__(256) void k_focal(const float* __restrict__ sims, const int* __restrict__ counts,
                                               const int* __restrict__ indexes, const int* __restrict__ labels,
                                               float* __restrict__ out) {
    __shared__ float lds4[4];
    __shared__ float s_et;
    int b = blockIdx.x, tid = threadIdx.x;
    int t = labels[indexes[b]];
    const float* srow = sims + (size_t)b * NCLUST;

    float X[32];
    float local = 0.f;
    for (int r = 0; r < 32; r++) {
        int i = r * 256 + tid;
        float v = srow[i];
        bool m = counts[i] > 0;
        float x = (i == t || !m) ? 0.0f : expf(v);
        if (i == t) s_et = expf(v);  // target cluster always non-empty
        X[r] = x;
        local += x;
    }
    float S = block_sum(local, lds4);  // barriers inside also publish s_et
    float T = TOPP * S;

    // bisection on float bit space: find boundary value x* where desc-cumsum crosses T
    unsigned lo = 0u, hi = 0x7F800000u;  // invariant: G(lo) >= T, G(hi) < T
    for (int it = 0; it < 31; it++) {
        unsigned mid = lo + ((hi - lo) >> 1);
        float v = __uint_as_float(mid);
        float g = 0.f;
        for (int r = 0; r < 32; r++) g += (X[r] >= v) ? X[r] : 0.f;
        g = block_sum(g, lds4);
        if (g >= T) lo = mid; else hi = mid;
    }
    float xs = __uint_as_float(lo);  // actual data value, > 0

    float sgt = 0.f, sge = 0.f, cgt = 0.f;
    for (int r = 0; r < 32; r++) {
        if (X[r] > xs) { sgt += X[r]; cgt += 1.f; }
        if (X[r] >= xs) sge += X[r];
    }
    sgt = block_sum(sgt, lds4);
    sge = block_sum(sge, lds4);
    cgt = block_sum(cgt, lds4);

    // crossing happens inside the run of values == xs:
    // csum candidates: sgt + j*xs, j = j0-1 and j0 (smallest j with sgt + j*xs >= T)
    float jf = (T - sgt) / xs;
    int j0 = (int)ceilf(jf);
    int mult = (int)rintf((sge - sgt) / xs);
    if (mult < 1) mult = 1;
    if (j0 < 1) j0 = 1;
    if (j0 > mult) j0 = mult;
    while (j0 > 1 && sgt + (float)(j0 - 1) * xs >= T) j0--;
    while (j0 < mult && sgt + (float)j0 * xs < T) j0++;
    float c_lo = sgt + (float)(j0 - 1) * xs;
    float c_hi = sgt + (float)j0 * xs;
    bool left_exists = ((int)cgt + j0) >= 2;                 // index i*-1 >= 0
    bool choose_left = left_exists && ((T - c_lo) <= (c_hi - T));  // argmin picks first on tie
    // if left candidate sits on the last element > x*, threshold = that element -> kept = sgt;
    // otherwise threshold = x* -> kept includes all ties -> sge
    float kept = (choose_left && j0 == 1) ? sgt : sge;

    if (tid == 0) {
        float et = s_et;
        float p = et / (et + kept + EPSC);
        float loss = -logf(p + EPSC);
        atomicAdd(out, loss * (1.0f / 256.0f));
    }
}

extern "C" void kernel_launch(void* const* d_in, const int* in_sizes, int n_in,
                              void* d_out, int out_size, void* d_ws, size_t ws_size,
                              hipStream_t stream) {
    const float* results = (const float*)d_in[0];
    const float* features = (const float*)d_in[1];
    const int* indexes = (const int*)d_in[2];
    const int* labels = (const int*)d_in[3];
    float* out = (float*)d_out;

    char* ws = (char*)d_ws;
    size_t off = 0;
    auto alloc = [&](size_t bytes) -> void* {
        void* p = ws + off;
        off += (bytes + 255) & ~(size_t)255;
        return p;
    };
    unsigned short* inputsB = (unsigned short*)alloc((size_t)BATCH * DIM * 2);
    unsigned short* FsumB = (unsigned short*)alloc((size_t)NCLUST * DIM * 2);
    float* sims = (float*)alloc((size_t)BATCH * NCLUST * 4);
    int* counts = (int*)alloc((size_t)NCLUST * 4);
    int* offsets = (int*)alloc((size_t)NCLUST * 4);
    int* cursor = (int*)alloc((size_t)NCLUST * 4);
    int* idxlist = (int*)alloc((size_t)NFEAT * 4);

    k_init<<<dim3(NCLUST / 256), dim3(256), 0, stream>>>(counts, out);
    k_normhist<<<dim3(BATCH), dim3(256), 0, stream>>>(results, inputsB, labels, counts);
    k_scan<<<dim3(1), dim3(256), 0, stream>>>(counts, offsets, cursor);
    k_scatter<<<dim3(NFEAT / 256), dim3(256), 0, stream>>>(labels, cursor, idxlist);
    k_csum<<<dim3(NCLUST), dim3(256), 0, stream>>>(features, counts, offsets, idxlist, FsumB);
    k_gemm<<<dim3(NCLUST / BN, BATCH / BM), dim3(256), 0, stream>>>(inputsB, FsumB, sims);
    k_focal<<<dim3(BATCH), dim3(256), 0, stream>>>(sims, counts, indexes, labels, out);
}